// Round 2
// baseline (2263.202 us; speedup 1.0000x reference)
//
#include <hip/hip_runtime.h>
#include <hip/hip_bf16.h>

#define DEV __device__ __forceinline__

DEV float b2f(__hip_bfloat16 x) { return __bfloat162float(x); }
DEV float ldflex(const void* p, long i, int bf) {
    return bf ? __bfloat162float(((const __hip_bfloat16*)p)[i]) : ((const float*)p)[i];
}
DEV float ldv(const float* p) { return *p; }
DEV float ldv(const __hip_bfloat16* p) { return __bfloat162float(*p); }
DEV void stv(float* p, float v) { *p = v; }
DEV void stv(__hip_bfloat16* p, float v) { *p = __float2bfloat16(v); }

// ---------------- dtype probe: bf16 vs f32 float buffers ----------------
__global__ void detect_dtype(const void* probe, int* flag) {
    if (blockIdx.x == 0 && threadIdx.x == 0) {
        const unsigned short* u = (const unsigned short*)probe;
        int sane = 0;
        for (int i = 0; i < 256; ++i) {
            unsigned short v = u[i];
            int e = (v >> 7) & 0xFF;               // bf16 exponent field
            if (v == 0 || (e >= 107 && e <= 147)) sane++;  // |x| in [2^-20, 2^20]
        }
        *flag = (sane >= 192) ? 1 : 0;             // 1 = bf16 storage
    }
}

// ---------------- VFE: per-voxel point lists ----------------
__global__ void build_lists(const int* __restrict__ p2v, int* __restrict__ cnt,
                            int* __restrict__ mini, int* __restrict__ list, int n) {
    int i = blockIdx.x * blockDim.x + threadIdx.x;
    if (i >= n) return;
    int v = p2v[i];
    int slot = atomicAdd(&cnt[v], 1);
    if (slot < 20) list[v * 20 + slot] = i;
    atomicMin(&mini[v], i);
}

__global__ void scatter_idx(const int* __restrict__ coors, int* __restrict__ idxmap) {
    int v = blockIdx.x * blockDim.x + threadIdx.x;
    if (v >= 40000) return;
    int x = coors[v * 4 + 1], y = coors[v * 4 + 2], z = coors[v * 4 + 3];
    idxmap[((size_t)z * 256 + y) * 256 + x] = v;
}

// ---------------- VFE encode: h[o*V + v] ----------------
__global__ void vfe_kernel(const void* __restrict__ points, const void* __restrict__ voxels,
                           const void* __restrict__ w_in, const void* __restrict__ s_in,
                           const void* __restrict__ t_in,
                           const int* __restrict__ cnt, const int* __restrict__ mini,
                           const int* __restrict__ list,
                           float* __restrict__ hbuf, const int* __restrict__ flagp) {
    const int V = 40000, S = 20, N = 200000;
    int v = blockIdx.x * blockDim.x + threadIdx.x;
    int o = blockIdx.y;
    if (v >= V) return;
    int bf = *flagp;
    float w[8];
#pragma unroll
    for (int c = 0; c < 8; ++c) w[c] = ldflex(w_in, o * 8 + c, bf);
    float sc = ldflex(s_in, o, bf), bi = ldflex(t_in, o, bf);
    float vx0 = ldflex(voxels, v * 4 + 0, bf);
    float vx1 = ldflex(voxels, v * 4 + 1, bf);
    float vx2 = ldflex(voxels, v * 4 + 2, bf);
    float vx3 = ldflex(voxels, v * 4 + 3, bf);
    int c_ = min(cnt[v], S);
    int first = mini[v];
    float acc = 0.f;
    for (int k = 0; k < c_; ++k) {
        int p = list[v * S + k];
        float p0 = ldflex(points, p, bf);
        float p1 = ldflex(points, N + p, bf);
        float p2 = ldflex(points, 2 * N + p, bf);
        float p3 = ldflex(points, 3 * N + p, bf);
        float dsum = w[0] * (vx0 - p0) + w[1] * (vx1 - p1) + w[2] * (vx2 - p2) +
                     w[3] * (vx3 - p3) + w[4] * p0 + w[5] * p1 + w[6] * p2 + w[7] * p3;
        float r = fmaxf(dsum * sc + bi, 0.f);
        acc += (p == first) ? r * (float)(S - c_ + 1) : r;   // padding replicates first point
    }
    hbuf[(size_t)o * V + v] = acc * (1.f / (float)S);
}

// ---------------- occupancy pools ----------------
__global__ void pool_occ0(const int* __restrict__ idxmap, float* __restrict__ out) {
    // in: idxmap (16,256,256); out: (8,128,128), stride 2, pad 1
    int idx = blockIdx.x * blockDim.x + threadIdx.x;
    if (idx >= 8 * 128 * 128) return;
    int w = idx % 128; int r = idx / 128;
    int h = r % 128;   int d = r / 128;
    float m = 0.f;
    for (int kd = 0; kd < 3; ++kd) {
        int id = d * 2 + kd - 1;
        if (id < 0 || id >= 16) continue;
        for (int kh = 0; kh < 3; ++kh) {
            int ih = h * 2 + kh - 1;
            if (ih < 0 || ih >= 256) continue;
            for (int kw = 0; kw < 3; ++kw) {
                int iw = w * 2 + kw - 1;
                if (iw < 0 || iw >= 256) continue;
                if (idxmap[((size_t)id * 256 + ih) * 256 + iw] >= 0) m = 1.f;
            }
        }
    }
    out[idx] = m;
}

__global__ void pool_occ(const float* __restrict__ in, float* __restrict__ out,
                         int Di, int Hi, int Wi, int Do, int Ho, int Wo, int stride) {
    int idx = blockIdx.x * blockDim.x + threadIdx.x;
    int total = Do * Ho * Wo;
    if (idx >= total) return;
    int w = idx % Wo; int r = idx / Wo;
    int h = r % Ho;   int d = r / Ho;
    float m = 0.f;
    for (int kd = 0; kd < 3; ++kd) {
        int id = d * stride + kd - 1;
        if (id < 0 || id >= Di) continue;
        for (int kh = 0; kh < 3; ++kh) {
            int ih = h * stride + kh - 1;
            if (ih < 0 || ih >= Hi) continue;
            for (int kw = 0; kw < 3; ++kw) {
                int iw = w * stride + kw - 1;
                if (iw < 0 || iw >= Wi) continue;
                m = fmaxf(m, in[((size_t)id * Hi + ih) * Wi + iw]);
            }
        }
    }
    out[idx] = m;
}

// ---------------- stage-0a: sparse gather conv (16,256,256)->(8,128,128) ----------------
__global__ __launch_bounds__(256) void conv0_gather(
    const float* __restrict__ hbuf, const int* __restrict__ idxmap,
    float* __restrict__ out, const float* __restrict__ wts,
    const float* __restrict__ scale, const float* __restrict__ bias,
    const float* __restrict__ occ) {
    const int V = 40000, CIN = 32;
    int idx = blockIdx.x * 256 + threadIdx.x;
    if (idx >= 8 * 128 * 32) return;
    int w0 = (idx % 32) * 4; int r = idx / 32;
    int h = r % 128; int d = r / 128;
    int co0 = blockIdx.y * 8;

    float ocv[4];
    bool any = false;
#pragma unroll
    for (int x = 0; x < 4; ++x) {
        ocv[x] = occ[((size_t)d * 128 + h) * 128 + w0 + x];
        any = any || (ocv[x] != 0.f);
    }
    float acc[8][4];
#pragma unroll
    for (int j = 0; j < 8; ++j)
#pragma unroll
        for (int x = 0; x < 4; ++x) acc[j][x] = 0.f;

    if (any) {
        for (int kd = 0; kd < 3; ++kd) {
            int id = d * 2 + kd - 1;
            if (id < 0 || id >= 16) continue;
            for (int kh = 0; kh < 3; ++kh) {
                int ih = h * 2 + kh - 1;
                if (ih < 0 || ih >= 256) continue;
                const int* ip = idxmap + ((size_t)id * 256 + ih) * 256;
                int iv[9];
                int iwb = w0 * 2 - 1;
#pragma unroll
                for (int t = 0; t < 9; ++t) {
                    int iw = iwb + t;
                    iv[t] = (iw >= 0 && iw < 256) ? ip[iw] : -1;
                }
#pragma unroll 4
                for (int ci = 0; ci < CIN; ++ci) {
                    float row[9];
#pragma unroll
                    for (int t = 0; t < 9; ++t)
                        row[t] = (iv[t] >= 0) ? hbuf[(size_t)ci * V + iv[t]] : 0.f;
                    const float* wp = wts + ((size_t)co0 * CIN + ci) * 27 + (kd * 3 + kh) * 3;
#pragma unroll
                    for (int kw = 0; kw < 3; ++kw)
#pragma unroll
                        for (int j = 0; j < 8; ++j) {
                            float wv = wp[(size_t)j * CIN * 27 + kw];
#pragma unroll
                            for (int x = 0; x < 4; ++x)
                                acc[j][x] += row[x * 2 + kw] * wv;
                        }
                }
            }
        }
    }
#pragma unroll
    for (int j = 0; j < 8; ++j) {
        int co = co0 + j;
        float s = scale[co], b = bias[co];
#pragma unroll
        for (int x = 0; x < 4; ++x) {
            float vv = fmaxf(acc[j][x] * s + b, 0.f) * ocv[x];
            out[(((size_t)co * 8 + d) * 128 + h) * 128 + w0 + x] = vv;
        }
    }
}

// ---------------- dense conv3x3x3 + BN + ReLU + mask ----------------
template <int CIN, int CTILE, int WTILE, int STRIDE, typename TIN, typename TOUT>
__global__ __launch_bounds__(256) void conv3x3(
    const TIN* __restrict__ in, TOUT* __restrict__ out,
    const float* __restrict__ wts, const float* __restrict__ scale,
    const float* __restrict__ bias, const float* __restrict__ occ,
    int Din, int Hin, int Win, int Dout, int Hout, int Wout) {
    constexpr int ROWLEN = (WTILE - 1) * STRIDE + 3;
    int wq = Wout / WTILE;
    int idx = blockIdx.x * blockDim.x + threadIdx.x;
    int total = Dout * Hout * wq;
    if (idx >= total) return;
    int w0 = (idx % wq) * WTILE; int r = idx / wq;
    int h = r % Hout; int d = r / Hout;
    int co0 = blockIdx.y * CTILE;

    float ocv[WTILE];
    bool any = false;
#pragma unroll
    for (int x = 0; x < WTILE; ++x) {
        ocv[x] = occ[((size_t)d * Hout + h) * Wout + w0 + x];
        any = any || (ocv[x] != 0.f);
    }
    float acc[CTILE][WTILE];
#pragma unroll
    for (int j = 0; j < CTILE; ++j)
#pragma unroll
        for (int x = 0; x < WTILE; ++x) acc[j][x] = 0.f;

    if (any) {
#pragma unroll 2
        for (int ci = 0; ci < CIN; ++ci) {
            const TIN* inc = in + (size_t)ci * Din * Hin * Win;
#pragma unroll
            for (int kd = 0; kd < 3; ++kd) {
                int id = d * STRIDE + kd - 1;
                if (id < 0 || id >= Din) continue;
#pragma unroll
                for (int kh = 0; kh < 3; ++kh) {
                    int ih = h * STRIDE + kh - 1;
                    if (ih < 0 || ih >= Hin) continue;
                    const TIN* row_p = inc + ((size_t)id * Hin + ih) * Win;
                    float row[ROWLEN];
                    int iwb = w0 * STRIDE - 1;
#pragma unroll
                    for (int t = 0; t < ROWLEN; ++t) {
                        int iw = iwb + t;
                        row[t] = (iw >= 0 && iw < Win) ? ldv(&row_p[iw]) : 0.f;
                    }
                    const float* wp = wts + ((size_t)co0 * CIN + ci) * 27 + (kd * 3 + kh) * 3;
#pragma unroll
                    for (int kw = 0; kw < 3; ++kw)
#pragma unroll
                        for (int j = 0; j < CTILE; ++j) {
                            float wv = wp[(size_t)j * CIN * 27 + kw];
#pragma unroll
                            for (int x = 0; x < WTILE; ++x)
                                acc[j][x] += row[x * STRIDE + kw] * wv;
                        }
                }
            }
        }
    }
#pragma unroll
    for (int j = 0; j < CTILE; ++j) {
        int co = co0 + j;
        float s = scale[co], b = bias[co];
#pragma unroll
        for (int x = 0; x < WTILE; ++x) {
            float vv = fmaxf(acc[j][x] * s + b, 0.f) * ocv[x];
            stv(&out[(((size_t)co * Dout + d) * Hout + h) * Wout + w0 + x], vv);
        }
    }
}

// ---------------- final conv: (64 -> 128) at (2,32,32), flag-typed store ----------------
__global__ __launch_bounds__(256) void conv_final(
    const float* __restrict__ in, void* __restrict__ outv,
    const float* __restrict__ wts, const float* __restrict__ scale,
    const float* __restrict__ bias, const float* __restrict__ occ,
    const int* __restrict__ flagp) {
    int idx = blockIdx.x * 256 + threadIdx.x;
    if (idx >= 2048) return;
    int w = idx & 31; int r = idx >> 5;
    int h = r & 31;   int d = r >> 5;
    int co = blockIdx.y;
    float oc = occ[idx];
    float acc = 0.f;
    if (oc != 0.f) {
        for (int ci = 0; ci < 64; ++ci) {
            const float* inc = in + (size_t)ci * 2048;
            const float* wp = wts + ((size_t)co * 64 + ci) * 27;
#pragma unroll
            for (int kd = 0; kd < 3; ++kd) {
                int id = d + kd - 1;
                if (id < 0 || id >= 2) continue;
#pragma unroll
                for (int kh = 0; kh < 3; ++kh) {
                    int ih = h + kh - 1;
                    if (ih < 0 || ih >= 32) continue;
#pragma unroll
                    for (int kw = 0; kw < 3; ++kw) {
                        int iw = w + kw - 1;
                        if (iw < 0 || iw >= 32) continue;
                        acc += inc[((size_t)id * 32 + ih) * 32 + iw] * wp[kd * 9 + kh * 3 + kw];
                    }
                }
            }
        }
    }
    float vv = fmaxf(acc * scale[co] + bias[co], 0.f) * oc;
    size_t off = (size_t)co * 2048 + idx;
    if (*flagp) ((__hip_bfloat16*)outv)[off] = __float2bfloat16(vv);
    else        ((float*)outv)[off] = vv;
}

// ---------------- weight conversion ----------------
struct CvtDesc { const void* src; int n; int off; };
struct CvtArgs { CvtDesc d[30]; };

__global__ void cvt_weights(CvtArgs a, float* __restrict__ dst, const int* __restrict__ flagp) {
    CvtDesc de = a.d[blockIdx.y];
    int bf = *flagp;
    int i = blockIdx.x * blockDim.x + threadIdx.x;
    if (i < de.n) dst[de.off + i] = ldflex(de.src, i, bf);
}

// ---------------- launch ----------------
extern "C" void kernel_launch(void* const* d_in, const int* in_sizes, int n_in,
                              void* d_out, int out_size, void* d_ws, size_t ws_size,
                              hipStream_t stream) {
    const void* points = d_in[0];
    const void* voxels = d_in[1];
    const void* w_in   = d_in[2];
    const void* s_in   = d_in[3];
    const void* t_in   = d_in[4];
    const int* coors = (const int*)d_in[35];
    const int* p2v   = (const int*)d_in[36];

    char* ws = (char*)d_ws;
    float* wb     = (float*)(ws + 0);                      // 913600 f = 3,654,400 B
    float* hbuf   = (float*)(ws + 4194304);                // 32*40000 f = 5,120,000 B
    int*   idxmap = (int*)  (ws + 12582912);               // 16*256*256 = 4,194,304 B
    float* xA     = (float*)(ws + 16777216);               // 16 MiB
    float* xB     = (float*)(ws + 33554432);               // 16 MiB
    char*  aux    = ws + 50331648;
    float* occ1 = (float*)(aux + 0);                       // 524,288 B
    float* occ2 = (float*)(aux + 524288);                  // 65,536 B
    float* occ3 = (float*)(aux + 589824);                  // 8,192 B
    float* occ4 = (float*)(aux + 598016);                  // 8,192 B
    int*   cnt  = (int*)  (aux + 606208);                  // 160,000 B
    int*   mini = (int*)  (aux + 766208);                  // 160,000 B
    int*   list = (int*)  (aux + 926208);                  // 3,200,000 B
    int*   flag = (int*)  (aux + 4126208);                 // total ~51.9 MiB

    hipMemsetAsync(idxmap, 0xFF, 4194304, stream);         // -1
    hipMemsetAsync(cnt, 0, 160000, stream);
    hipMemsetAsync(mini, 0x7f, 160000, stream);            // 0x7f7f7f7f > N

    detect_dtype<<<1, 64, 0, stream>>>(points, flag);

    static const int widx[30] = {5,6,7, 8,9,10, 11,12,13, 14,15,16, 17,18,19,
                                 20,21,22, 23,24,25, 26,27,28, 29,30,31, 32,33,34};
    static const int woff[30] = {0,27648,27680, 27712,55360,55392, 55424,83072,83104,
                                 83136,138432,138496, 138560,249152,249216,
                                 249280,359872,359936, 360000,470592,470656,
                                 470720,581312,581376, 581440,692032,692096,
                                 692160,913344,913472};
    static const int wn[30]   = {27648,32,32, 27648,32,32, 27648,32,32,
                                 55296,64,64, 110592,64,64, 110592,64,64,
                                 110592,64,64, 110592,64,64, 110592,64,64,
                                 221184,128,128};
    CvtArgs ca;
    for (int i = 0; i < 30; ++i) ca.d[i] = CvtDesc{ d_in[widx[i]], wn[i], woff[i] };
    cvt_weights<<<dim3(864, 30), 256, 0, stream>>>(ca, wb, flag);

    build_lists<<<(200000 + 255) / 256, 256, 0, stream>>>(p2v, cnt, mini, list, 200000);
    scatter_idx<<<(40000 + 255) / 256, 256, 0, stream>>>(coors, idxmap);
    vfe_kernel<<<dim3(157, 32), 256, 0, stream>>>(points, voxels, w_in, s_in, t_in,
                                                  cnt, mini, list, hbuf, flag);

    // stage 0: (32,16,256,256) -> (32,8,128,128)
    pool_occ0<<<(131072 + 255) / 256, 256, 0, stream>>>(idxmap, occ1);
    conv0_gather<<<dim3(128, 4), 256, 0, stream>>>(hbuf, idxmap, xA,
                                                   wb + 0, wb + 27648, wb + 27680, occ1);
    conv3x3<32, 8, 4, 1, float, float><<<dim3(128, 4), 256, 0, stream>>>(
        xA, xB, wb + 27712, wb + 55360, wb + 55392, occ1, 8, 128, 128, 8, 128, 128);
    conv3x3<32, 8, 4, 1, float, float><<<dim3(128, 4), 256, 0, stream>>>(
        xB, xA, wb + 55424, wb + 83072, wb + 83104, occ1, 8, 128, 128, 8, 128, 128);

    // stage 1: -> (64,4,64,64)
    pool_occ<<<(16384 + 255) / 256, 256, 0, stream>>>(occ1, occ2, 8, 128, 128, 4, 64, 64, 2);
    conv3x3<32, 4, 4, 2, float, float><<<dim3(16, 16), 256, 0, stream>>>(
        xA, xB, wb + 83136, wb + 138432, wb + 138496, occ2, 8, 128, 128, 4, 64, 64);
    conv3x3<64, 4, 4, 1, float, float><<<dim3(16, 16), 256, 0, stream>>>(
        xB, xA, wb + 138560, wb + 249152, wb + 249216, occ2, 4, 64, 64, 4, 64, 64);
    conv3x3<64, 4, 4, 1, float, float><<<dim3(16, 16), 256, 0, stream>>>(
        xA, xB, wb + 249280, wb + 359872, wb + 359936, occ2, 4, 64, 64, 4, 64, 64);

    // stage 2: -> (64,2,32,32)
    pool_occ<<<(2048 + 255) / 256, 256, 0, stream>>>(occ2, occ3, 4, 64, 64, 2, 32, 32, 2);
    conv3x3<64, 1, 1, 2, float, float><<<dim3(8, 64), 256, 0, stream>>>(
        xB, xA, wb + 360000, wb + 470592, wb + 470656, occ3, 4, 64, 64, 2, 32, 32);
    conv3x3<64, 1, 1, 1, float, float><<<dim3(8, 64), 256, 0, stream>>>(
        xA, xB, wb + 470720, wb + 581312, wb + 581376, occ3, 2, 32, 32, 2, 32, 32);
    conv3x3<64, 1, 1, 1, float, float><<<dim3(8, 64), 256, 0, stream>>>(
        xB, xA, wb + 581440, wb + 692032, wb + 692096, occ3, 2, 32, 32, 2, 32, 32);

    // final: -> (128,2,32,32)
    pool_occ<<<(2048 + 255) / 256, 256, 0, stream>>>(occ3, occ4, 2, 32, 32, 2, 32, 32, 1);
    conv_final<<<dim3(8, 128), 256, 0, stream>>>(xA, d_out, wb + 692160, wb + 913344,
                                                 wb + 913472, occ4, flag);
}

// Round 3
// 1679.733 us; speedup vs baseline: 1.3474x; 1.3474x over previous
//
#include <hip/hip_runtime.h>
#include <hip/hip_bf16.h>

#define DEV __device__ __forceinline__

DEV float ldflex(const void* p, long i, int bf) {
    return bf ? __bfloat162float(((const __hip_bfloat16*)p)[i]) : ((const float*)p)[i];
}

// ---------------- dtype probe: bf16 vs f32 float buffers ----------------
__global__ void detect_dtype(const void* probe, int* flag) {
    if (blockIdx.x == 0 && threadIdx.x == 0) {
        const unsigned short* u = (const unsigned short*)probe;
        int sane = 0;
        for (int i = 0; i < 256; ++i) {
            unsigned short v = u[i];
            int e = (v >> 7) & 0xFF;
            if (v == 0 || (e >= 107 && e <= 147)) sane++;
        }
        *flag = (sane >= 192) ? 1 : 0;   // 1 = bf16 storage
    }
}

// ---------------- weight conversion + transpose to [tap][ci][co] ----------------
struct CvtDesc { const void* src; int n; int off; int cin; int cout; };  // cin==0: plain copy
struct CvtArgs { CvtDesc d[30]; };

__global__ void cvt_weights(CvtArgs a, float* __restrict__ dst, const int* __restrict__ flagp) {
    CvtDesc de = a.d[blockIdx.y];
    int bf = *flagp;
    int i = blockIdx.x * blockDim.x + threadIdx.x;
    if (i >= de.n) return;
    float v = ldflex(de.src, i, bf);
    if (de.cin == 0) { dst[de.off + i] = v; return; }
    int co = i / (de.cin * 27);
    int rem = i % (de.cin * 27);
    int ci = rem / 27, tap = rem % 27;
    dst[de.off + (tap * de.cin + ci) * de.cout + co] = v;
}

// ---------------- point lists ----------------
__global__ void build_lists(const int* __restrict__ p2v, int* __restrict__ cnt,
                            int* __restrict__ mini, int* __restrict__ list, int n) {
    int i = blockIdx.x * blockDim.x + threadIdx.x;
    if (i >= n) return;
    int v = p2v[i];
    int slot = atomicAdd(&cnt[v], 1);
    if (slot < 20) list[v * 20 + slot] = i;
    atomicMin(&mini[v], i);
}

__global__ void scatter_idx(const int* __restrict__ coors, int* __restrict__ idxmap) {
    int v = blockIdx.x * blockDim.x + threadIdx.x;
    if (v >= 40000) return;
    int x = coors[v * 4 + 1], y = coors[v * 4 + 2], z = coors[v * 4 + 3];
    idxmap[((size_t)z * 256 + y) * 256 + x] = v;
}

// ---------------- VFE: one thread per voxel, voxel-major output h[v][32] ----------------
__global__ __launch_bounds__(256) void vfe_kernel(
    const void* __restrict__ points, const void* __restrict__ voxels,
    const void* __restrict__ w_in, const void* __restrict__ s_in, const void* __restrict__ t_in,
    const int* __restrict__ cnt, const int* __restrict__ mini, const int* __restrict__ list,
    float* __restrict__ hbuf, const int* __restrict__ flagp) {
    const int V = 40000, S = 20, N = 200000;
    int v = blockIdx.x * blockDim.x + threadIdx.x;
    if (v >= V) return;
    int bf = *flagp;
    float vx0 = ldflex(voxels, v * 4 + 0, bf);
    float vx1 = ldflex(voxels, v * 4 + 1, bf);
    float vx2 = ldflex(voxels, v * 4 + 2, bf);
    float vx3 = ldflex(voxels, v * 4 + 3, bf);
    int c_ = min(cnt[v], S);
    int first = mini[v];
    float acc[32];
#pragma unroll
    for (int o = 0; o < 32; ++o) acc[o] = 0.f;

    for (int base = 0; base < c_; base += 5) {
        int kn = min(5, c_ - base);
        float f[5][8], mult[5];
#pragma unroll
        for (int k = 0; k < 5; ++k) {
            if (k < kn) {
                int p = list[v * S + base + k];
                float p0 = ldflex(points, p, bf);
                float p1 = ldflex(points, N + p, bf);
                float p2 = ldflex(points, 2 * N + p, bf);
                float p3 = ldflex(points, 3 * N + p, bf);
                f[k][0] = vx0 - p0; f[k][1] = vx1 - p1; f[k][2] = vx2 - p2; f[k][3] = vx3 - p3;
                f[k][4] = p0; f[k][5] = p1; f[k][6] = p2; f[k][7] = p3;
                mult[k] = (p == first) ? (float)(S - c_ + 1) : 1.f;
            } else {
#pragma unroll
                for (int c = 0; c < 8; ++c) f[k][c] = 0.f;
                mult[k] = 0.f;
            }
        }
#pragma unroll 4
        for (int o = 0; o < 32; ++o) {
            float w[8];
#pragma unroll
            for (int c = 0; c < 8; ++c) w[c] = ldflex(w_in, o * 8 + c, bf);
            float sc = ldflex(s_in, o, bf), bi = ldflex(t_in, o, bf);
#pragma unroll
            for (int k = 0; k < 5; ++k) {
                float d = f[k][0] * w[0] + f[k][1] * w[1] + f[k][2] * w[2] + f[k][3] * w[3] +
                          f[k][4] * w[4] + f[k][5] * w[5] + f[k][6] * w[6] + f[k][7] * w[7];
                acc[o] += fmaxf(d * sc + bi, 0.f) * mult[k];
            }
        }
    }
#pragma unroll
    for (int o = 0; o < 32; ++o) hbuf[(size_t)v * 32 + o] = acc[o] * 0.05f;
}

// ---------------- occupancy pools ----------------
__global__ void pool_occ0(const int* __restrict__ idxmap, float* __restrict__ out) {
    int idx = blockIdx.x * blockDim.x + threadIdx.x;
    if (idx >= 8 * 128 * 128) return;
    int w = idx % 128; int r = idx / 128;
    int h = r % 128;   int d = r / 128;
    float m = 0.f;
    for (int kd = 0; kd < 3; ++kd) {
        int id = d * 2 + kd - 1;
        if (id < 0 || id >= 16) continue;
        for (int kh = 0; kh < 3; ++kh) {
            int ih = h * 2 + kh - 1;
            if (ih < 0 || ih >= 256) continue;
            for (int kw = 0; kw < 3; ++kw) {
                int iw = w * 2 + kw - 1;
                if (iw < 0 || iw >= 256) continue;
                if (idxmap[((size_t)id * 256 + ih) * 256 + iw] >= 0) m = 1.f;
            }
        }
    }
    out[idx] = m;
}

__global__ void pool_occ(const float* __restrict__ in, float* __restrict__ out,
                         int Di, int Hi, int Wi, int Do, int Ho, int Wo, int stride) {
    int idx = blockIdx.x * blockDim.x + threadIdx.x;
    int total = Do * Ho * Wo;
    if (idx >= total) return;
    int w = idx % Wo; int r = idx / Wo;
    int h = r % Ho;   int d = r / Ho;
    float m = 0.f;
    for (int kd = 0; kd < 3; ++kd) {
        int id = d * stride + kd - 1;
        if (id < 0 || id >= Di) continue;
        for (int kh = 0; kh < 3; ++kh) {
            int ih = h * stride + kh - 1;
            if (ih < 0 || ih >= Hi) continue;
            for (int kw = 0; kw < 3; ++kw) {
                int iw = w * stride + kw - 1;
                if (iw < 0 || iw >= Wi) continue;
                m = fmaxf(m, in[((size_t)id * Hi + ih) * Wi + iw]);
            }
        }
    }
    out[idx] = m;
}

// ---------------- stage-0a: gather conv, all 32 couts per thread ----------------
__global__ __launch_bounds__(256) void conv0_gather(
    const float* __restrict__ hbuf, const int* __restrict__ idxmap,
    float* __restrict__ out, const float* __restrict__ wT,   // [tap][ci][co], 27*32*32
    const float* __restrict__ scale, const float* __restrict__ bias,
    const float* __restrict__ occ) {
    int idx = blockIdx.x * 256 + threadIdx.x;   // 131072 exact
    int w = idx & 127; int r = idx >> 7;
    int h = r & 127;   int d = r >> 7;
    float oc = occ[idx];
    float acc[32];
#pragma unroll
    for (int j = 0; j < 32; ++j) acc[j] = 0.f;

    if (__ballot(oc != 0.f)) {
        for (int kd = 0; kd < 3; ++kd) {
            int id = d * 2 + kd - 1;
            if (id < 0 || id >= 16) continue;          // wave-uniform
            for (int kh = 0; kh < 3; ++kh) {
                int ih = h * 2 + kh - 1;
                if (ih < 0 || ih >= 256) continue;     // wave-uniform
                const int* ip = idxmap + ((size_t)id * 256 + ih) * 256;
                for (int kw = 0; kw < 3; ++kw) {
                    int iw = w * 2 + kw - 1;
                    int v = (iw >= 0 && iw < 256 && oc != 0.f) ? ip[iw] : -1;
                    if (__ballot(v >= 0) == 0ULL) continue;
                    float m = (v >= 0) ? 1.f : 0.f;
                    const float4* hp = (const float4*)(hbuf + (size_t)(v >= 0 ? v : 0) * 32);
                    float4 hv[8];
#pragma unroll
                    for (int q = 0; q < 8; ++q) {
                        hv[q] = hp[q];
                        hv[q].x *= m; hv[q].y *= m; hv[q].z *= m; hv[q].w *= m;
                    }
                    const float* wb = wT + (size_t)((kd * 3 + kh) * 3 + kw) * 1024;
#pragma unroll
                    for (int ci = 0; ci < 32; ++ci) {
                        float hvv = ((const float*)hv)[ci];  // constant index after unroll
#pragma unroll
                        for (int j = 0; j < 32; ++j)
                            acc[j] += hvv * wb[ci * 32 + j];
                    }
                }
            }
        }
    }
#pragma unroll
    for (int j = 0; j < 32; ++j)
        out[(size_t)j * 131072 + idx] = fmaxf(acc[j] * scale[j] + bias[j], 0.f) * oc;
}

// ---------------- dense conv: WTILE=1, T couts/thread, wT layout [tap][ci][co] ----------------
template <int CIN, int COUT, int T, int STRIDE>
__global__ __launch_bounds__(256) void convd(
    const float* __restrict__ in, float* __restrict__ out,
    const float* __restrict__ wT, const float* __restrict__ scale,
    const float* __restrict__ bias, const float* __restrict__ occ,
    int Din, int Hin, int Win, int Dout, int Hout, int Wout) {
    int idx = blockIdx.x * 256 + threadIdx.x;
    int total = Dout * Hout * Wout;
    if (idx >= total) return;
    int w = idx % Wout; int r = idx / Wout;
    int h = r % Hout;   int d = r / Hout;
    int co0 = blockIdx.y * T;
    float oc = occ[idx];
    float acc[T];
#pragma unroll
    for (int j = 0; j < T; ++j) acc[j] = 0.f;

    if (oc != 0.f) {
        for (int kd = 0; kd < 3; ++kd) {
            int id = d * STRIDE + kd - 1;
            if (id < 0 || id >= Din) continue;
            for (int kh = 0; kh < 3; ++kh) {
                int ih = h * STRIDE + kh - 1;
                if (ih < 0 || ih >= Hin) continue;
                int tapb = ((kd * 3 + kh) * 3) * CIN * COUT;
#pragma unroll 4
                for (int ci = 0; ci < CIN; ++ci) {
                    const float* rp = in + ((size_t)(ci * Din + id) * Hin + ih) * Win;
                    float rv[3];
#pragma unroll
                    for (int t = 0; t < 3; ++t) {
                        int iw = w * STRIDE + t - 1;
                        rv[t] = (iw >= 0 && iw < Win) ? rp[iw] : 0.f;
                    }
#pragma unroll
                    for (int kw = 0; kw < 3; ++kw) {
                        const float* wb = wT + tapb + (kw * CIN + ci) * COUT + co0;
#pragma unroll
                        for (int j = 0; j < T; ++j) acc[j] += rv[kw] * wb[j];
                    }
                }
            }
        }
    }
#pragma unroll
    for (int j = 0; j < T; ++j) {
        int co = co0 + j;
        out[(size_t)co * total + idx] = fmaxf(acc[j] * scale[co] + bias[co], 0.f) * oc;
    }
}

// ---------------- final conv 64->128 at (2,32,32), typed store ----------------
__global__ __launch_bounds__(256) void conv_final(
    const float* __restrict__ in, void* __restrict__ outv,
    const float* __restrict__ wT, const float* __restrict__ scale,
    const float* __restrict__ bias, const float* __restrict__ occ,
    const int* __restrict__ flagp) {
    int idx = blockIdx.x * 256 + threadIdx.x;   // 2048 exact
    int w = idx & 31; int r = idx >> 5;
    int h = r & 31;   int d = r >> 5;
    int co0 = blockIdx.y * 4;
    float oc = occ[idx];
    float acc[4] = {0.f, 0.f, 0.f, 0.f};
    if (oc != 0.f) {
        for (int kd = 0; kd < 3; ++kd) {
            int id = d + kd - 1;
            if (id < 0 || id >= 2) continue;
            for (int kh = 0; kh < 3; ++kh) {
                int ih = h + kh - 1;
                if (ih < 0 || ih >= 32) continue;
                int tapb = ((kd * 3 + kh) * 3) * 64 * 128;
#pragma unroll 4
                for (int ci = 0; ci < 64; ++ci) {
                    const float* rp = in + ((size_t)(ci * 2 + id) * 32 + ih) * 32;
                    float rv[3];
#pragma unroll
                    for (int t = 0; t < 3; ++t) {
                        int iw = w + t - 1;
                        rv[t] = (iw >= 0 && iw < 32) ? rp[iw] : 0.f;
                    }
#pragma unroll
                    for (int kw = 0; kw < 3; ++kw) {
                        const float* wb = wT + tapb + (kw * 64 + ci) * 128 + co0;
#pragma unroll
                        for (int j = 0; j < 4; ++j) acc[j] += rv[kw] * wb[j];
                    }
                }
            }
        }
    }
    int bf = *flagp;
#pragma unroll
    for (int j = 0; j < 4; ++j) {
        int co = co0 + j;
        float vv = fmaxf(acc[j] * scale[co] + bias[co], 0.f) * oc;
        size_t off = (size_t)co * 2048 + idx;
        if (bf) ((__hip_bfloat16*)outv)[off] = __float2bfloat16(vv);
        else    ((float*)outv)[off] = vv;
    }
}

// ---------------- launch ----------------
extern "C" void kernel_launch(void* const* d_in, const int* in_sizes, int n_in,
                              void* d_out, int out_size, void* d_ws, size_t ws_size,
                              hipStream_t stream) {
    const void* points = d_in[0];
    const void* voxels = d_in[1];
    const void* w_in   = d_in[2];
    const void* s_in   = d_in[3];
    const void* t_in   = d_in[4];
    const int* coors = (const int*)d_in[35];
    const int* p2v   = (const int*)d_in[36];

    char* ws = (char*)d_ws;
    float* wb     = (float*)(ws + 0);                      // 913,600 floats
    float* hbuf   = (float*)(ws + 4194304);                // 40000*32 f (voxel-major)
    int*   idxmap = (int*)  (ws + 12582912);               // 16*256*256
    float* xA     = (float*)(ws + 16777216);               // 16 MiB
    float* xB     = (float*)(ws + 33554432);               // 16 MiB
    char*  aux    = ws + 50331648;
    float* occ1 = (float*)(aux + 0);
    float* occ2 = (float*)(aux + 524288);
    float* occ3 = (float*)(aux + 589824);
    float* occ4 = (float*)(aux + 598016);
    int*   cnt  = (int*)  (aux + 606208);
    int*   mini = (int*)  (aux + 766208);
    int*   list = (int*)  (aux + 926208);
    int*   flag = (int*)  (aux + 4126208);

    hipMemsetAsync(idxmap, 0xFF, 4194304, stream);
    hipMemsetAsync(cnt, 0, 160000, stream);
    hipMemsetAsync(mini, 0x7f, 160000, stream);

    detect_dtype<<<1, 64, 0, stream>>>(points, flag);

    static const int widx[30] = {5,6,7, 8,9,10, 11,12,13, 14,15,16, 17,18,19,
                                 20,21,22, 23,24,25, 26,27,28, 29,30,31, 32,33,34};
    static const int woff[30] = {0,27648,27680, 27712,55360,55392, 55424,83072,83104,
                                 83136,138432,138496, 138560,249152,249216,
                                 249280,359872,359936, 360000,470592,470656,
                                 470720,581312,581376, 581440,692032,692096,
                                 692160,913344,913472};
    static const int wn[30]   = {27648,32,32, 27648,32,32, 27648,32,32,
                                 55296,32,64, 110592,64,64, 110592,64,64,
                                 110592,64,64, 110592,64,64, 110592,64,64,
                                 221184,64,128};
    // cin/cout for conv descs (0 = plain copy for BN vectors)
    static const int wcin[30]  = {32,0,0, 32,0,0, 32,0,0, 32,0,0, 64,0,0,
                                  64,0,0, 64,0,0, 64,0,0, 64,0,0, 64,0,0};
    static const int wcout[30] = {32,0,0, 32,0,0, 32,0,0, 64,0,0, 64,0,0,
                                  64,0,0, 64,0,0, 64,0,0, 64,0,0, 128,0,0};
    // fix wn for BN entries (scale/bias counts)
    static const int wnfix[30] = {27648,32,32, 27648,32,32, 27648,32,32,
                                  55296,64,64, 110592,64,64, 110592,64,64,
                                  110592,64,64, 110592,64,64, 110592,64,64,
                                  221184,128,128};
    (void)wn;
    CvtArgs ca;
    for (int i = 0; i < 30; ++i)
        ca.d[i] = CvtDesc{ d_in[widx[i]], wnfix[i], woff[i], wcin[i], wcout[i] };
    cvt_weights<<<dim3(864, 30), 256, 0, stream>>>(ca, wb, flag);

    build_lists<<<(200000 + 255) / 256, 256, 0, stream>>>(p2v, cnt, mini, list, 200000);
    scatter_idx<<<(40000 + 255) / 256, 256, 0, stream>>>(coors, idxmap);
    vfe_kernel<<<160, 256, 0, stream>>>(points, voxels, w_in, s_in, t_in,
                                        cnt, mini, list, hbuf, flag);

    // stage 0: -> (32,8,128,128)
    pool_occ0<<<512, 256, 0, stream>>>(idxmap, occ1);
    conv0_gather<<<512, 256, 0, stream>>>(hbuf, idxmap, xA, wb + 0, wb + 27648, wb + 27680, occ1);
    convd<32, 32, 32, 1><<<dim3(512, 1), 256, 0, stream>>>(
        xA, xB, wb + 27712, wb + 55360, wb + 55392, occ1, 8, 128, 128, 8, 128, 128);
    convd<32, 32, 32, 1><<<dim3(512, 1), 256, 0, stream>>>(
        xB, xA, wb + 55424, wb + 83072, wb + 83104, occ1, 8, 128, 128, 8, 128, 128);

    // stage 1: -> (64,4,64,64)
    pool_occ<<<64, 256, 0, stream>>>(occ1, occ2, 8, 128, 128, 4, 64, 64, 2);
    convd<32, 64, 8, 2><<<dim3(64, 8), 256, 0, stream>>>(
        xA, xB, wb + 83136, wb + 138432, wb + 138496, occ2, 8, 128, 128, 4, 64, 64);
    convd<64, 64, 8, 1><<<dim3(64, 8), 256, 0, stream>>>(
        xB, xA, wb + 138560, wb + 249152, wb + 249216, occ2, 4, 64, 64, 4, 64, 64);
    convd<64, 64, 8, 1><<<dim3(64, 8), 256, 0, stream>>>(
        xA, xB, wb + 249280, wb + 359872, wb + 359936, occ2, 4, 64, 64, 4, 64, 64);

    // stage 2: -> (64,2,32,32)
    pool_occ<<<8, 256, 0, stream>>>(occ2, occ3, 4, 64, 64, 2, 32, 32, 2);
    convd<64, 64, 2, 2><<<dim3(8, 32), 256, 0, stream>>>(
        xB, xA, wb + 360000, wb + 470592, wb + 470656, occ3, 4, 64, 64, 2, 32, 32);
    convd<64, 64, 2, 1><<<dim3(8, 32), 256, 0, stream>>>(
        xA, xB, wb + 470720, wb + 581312, wb + 581376, occ3, 2, 32, 32, 2, 32, 32);
    convd<64, 64, 2, 1><<<dim3(8, 32), 256, 0, stream>>>(
        xB, xA, wb + 581440, wb + 692032, wb + 692096, occ3, 2, 32, 32, 2, 32, 32);

    // final: -> (128,2,32,32)
    pool_occ<<<8, 256, 0, stream>>>(occ3, occ4, 2, 32, 32, 2, 32, 32, 1);
    conv_final<<<dim3(8, 32), 256, 0, stream>>>(xA, d_out, wb + 692160, wb + 913344,
                                                wb + 913472, occ4, flag);
}

// Round 5
// 506.339 us; speedup vs baseline: 4.4697x; 3.3174x over previous
//
#include <hip/hip_runtime.h>
#include <hip/hip_bf16.h>

#define DEV __device__ __forceinline__

typedef __bf16 bf16x8 __attribute__((ext_vector_type(8)));
typedef float f32x4 __attribute__((ext_vector_type(4)));

DEV float ldflex(const void* p, long i, int bf) {
    return bf ? __bfloat162float(((const __hip_bfloat16*)p)[i]) : ((const float*)p)[i];
}
DEV bf16x8 ldfrag(const __hip_bfloat16* p) { return *(const bf16x8*)(const void*)p; }

// ---------------- dtype probe ----------------
__global__ void detect_dtype(const void* probe, int* flag) {
    if (blockIdx.x == 0 && threadIdx.x == 0) {
        const unsigned short* u = (const unsigned short*)probe;
        int sane = 0;
        for (int i = 0; i < 256; ++i) {
            unsigned short v = u[i];
            int e = (v >> 7) & 0xFF;
            if (v == 0 || (e >= 107 && e <= 147)) sane++;
        }
        *flag = (sane >= 192) ? 1 : 0;   // 1 = bf16 storage
    }
}

// ---------------- weight conversion into MFMA B-fragment order ----------------
// conv weights (cin>0): wf[off + (((tap*KB+kb)*NH+half)<<9) + lane*8 + j] bf16,
//   co=half*16+n, ci=kb*32+q*8+j, lane=q*16+n.  BN (cin==0): bn[off+i] f32.
struct CvtDesc { const void* src; int n; int off; int cin; int cout; };
struct CvtArgs { CvtDesc d[30]; };

__global__ void cvt_weights(CvtArgs a, __hip_bfloat16* __restrict__ wf,
                            float* __restrict__ bn, const int* __restrict__ flagp) {
    CvtDesc de = a.d[blockIdx.y];
    int i = blockIdx.x * 256 + threadIdx.x;
    if (i >= de.n) return;
    float v = ldflex(de.src, i, *flagp);
    if (de.cin == 0) { bn[de.off + i] = v; return; }
    int cin = de.cin;
    int KB = cin >> 5, NH = de.cout >> 4;
    int co = i / (cin * 27);
    int rem = i % (cin * 27);
    int ci = rem / 27, tap = rem % 27;
    int kb = ci >> 5, q = (ci >> 3) & 3, j = ci & 7;
    int half = co >> 4, n = co & 15, lane = q * 16 + n;
    (void)KB;
    wf[de.off + ((((tap * KB + kb) * NH + half) << 9) + lane * 8 + j)] = __float2bfloat16(v);
}

// ---------------- point lists ----------------
__global__ void build_lists(const int* __restrict__ p2v, int* __restrict__ cnt,
                            int* __restrict__ mini, int* __restrict__ list, int n) {
    int i = blockIdx.x * blockDim.x + threadIdx.x;
    if (i >= n) return;
    int v = p2v[i];
    int slot = atomicAdd(&cnt[v], 1);
    if (slot < 20) list[v * 20 + slot] = i;
    atomicMin(&mini[v], i);
}

__global__ void scatter_idx(const int* __restrict__ coors, int* __restrict__ idxmap) {
    int v = blockIdx.x * blockDim.x + threadIdx.x;
    if (v >= 40000) return;
    int x = coors[v * 4 + 1], y = coors[v * 4 + 2], z = coors[v * 4 + 3];
    idxmap[((size_t)z * 256 + y) * 256 + x] = v;
}

// ---------------- VFE: one thread per voxel, bf16 voxel-major h[v][32] ----------------
__global__ __launch_bounds__(256) void vfe_kernel(
    const void* __restrict__ points, const void* __restrict__ voxels,
    const void* __restrict__ w_in, const void* __restrict__ s_in, const void* __restrict__ t_in,
    const int* __restrict__ cnt, const int* __restrict__ mini, const int* __restrict__ list,
    __hip_bfloat16* __restrict__ hbuf, const int* __restrict__ flagp) {
    const int V = 40000, S = 20, N = 200000;
    int v = blockIdx.x * blockDim.x + threadIdx.x;
    if (v >= V) return;
    int bf = *flagp;
    float vx0 = ldflex(voxels, v * 4 + 0, bf);
    float vx1 = ldflex(voxels, v * 4 + 1, bf);
    float vx2 = ldflex(voxels, v * 4 + 2, bf);
    float vx3 = ldflex(voxels, v * 4 + 3, bf);
    int c_ = min(cnt[v], S);
    int first = mini[v];
    float acc[32];
#pragma unroll
    for (int o = 0; o < 32; ++o) acc[o] = 0.f;

    for (int base = 0; base < c_; base += 5) {
        int kn = min(5, c_ - base);
        float f[5][8], mult[5];
#pragma unroll
        for (int k = 0; k < 5; ++k) {
            if (k < kn) {
                int p = list[v * S + base + k];
                float p0 = ldflex(points, p, bf);
                float p1 = ldflex(points, N + p, bf);
                float p2 = ldflex(points, 2 * N + p, bf);
                float p3 = ldflex(points, 3 * N + p, bf);
                f[k][0] = vx0 - p0; f[k][1] = vx1 - p1; f[k][2] = vx2 - p2; f[k][3] = vx3 - p3;
                f[k][4] = p0; f[k][5] = p1; f[k][6] = p2; f[k][7] = p3;
                mult[k] = (p == first) ? (float)(S - c_ + 1) : 1.f;
            } else {
#pragma unroll
                for (int c = 0; c < 8; ++c) f[k][c] = 0.f;
                mult[k] = 0.f;
            }
        }
#pragma unroll 4
        for (int o = 0; o < 32; ++o) {
            float w[8];
#pragma unroll
            for (int c = 0; c < 8; ++c) w[c] = ldflex(w_in, o * 8 + c, bf);
            float sc = ldflex(s_in, o, bf), bi = ldflex(t_in, o, bf);
#pragma unroll
            for (int k = 0; k < 5; ++k) {
                float d = f[k][0] * w[0] + f[k][1] * w[1] + f[k][2] * w[2] + f[k][3] * w[3] +
                          f[k][4] * w[4] + f[k][5] * w[5] + f[k][6] * w[6] + f[k][7] * w[7];
                acc[o] += fmaxf(d * sc + bi, 0.f) * mult[k];
            }
        }
    }
#pragma unroll
    for (int o = 0; o < 32; ++o)
        hbuf[(size_t)v * 32 + o] = __float2bfloat16(acc[o] * 0.05f);
}

// ---------------- occupancy pools ----------------
__global__ void pool_occ0(const int* __restrict__ idxmap, float* __restrict__ out) {
    int idx = blockIdx.x * blockDim.x + threadIdx.x;
    if (idx >= 8 * 128 * 128) return;
    int w = idx % 128; int r = idx / 128;
    int h = r % 128;   int d = r / 128;
    float m = 0.f;
    for (int kd = 0; kd < 3; ++kd) {
        int id = d * 2 + kd - 1;
        if (id < 0 || id >= 16) continue;
        for (int kh = 0; kh < 3; ++kh) {
            int ih = h * 2 + kh - 1;
            if (ih < 0 || ih >= 256) continue;
            for (int kw = 0; kw < 3; ++kw) {
                int iw = w * 2 + kw - 1;
                if (iw < 0 || iw >= 256) continue;
                if (idxmap[((size_t)id * 256 + ih) * 256 + iw] >= 0) m = 1.f;
            }
        }
    }
    out[idx] = m;
}

__global__ void pool_occ(const float* __restrict__ in, float* __restrict__ out,
                         int Di, int Hi, int Wi, int Do, int Ho, int Wo, int stride) {
    int idx = blockIdx.x * blockDim.x + threadIdx.x;
    int total = Do * Ho * Wo;
    if (idx >= total) return;
    int w = idx % Wo; int r = idx / Wo;
    int h = r % Ho;   int d = r / Ho;
    float m = 0.f;
    for (int kd = 0; kd < 3; ++kd) {
        int id = d * stride + kd - 1;
        if (id < 0 || id >= Di) continue;
        for (int kh = 0; kh < 3; ++kh) {
            int ih = h * stride + kh - 1;
            if (ih < 0 || ih >= Hi) continue;
            for (int kw = 0; kw < 3; ++kw) {
                int iw = w * stride + kw - 1;
                if (iw < 0 || iw >= Wi) continue;
                m = fmaxf(m, in[((size_t)id * Hi + ih) * Wi + iw]);
            }
        }
    }
    out[idx] = m;
}

// ---------------- conv0: sparse gather implicit-GEMM MFMA ----------------
__global__ __launch_bounds__(256) void conv0_mfma(
    const __hip_bfloat16* __restrict__ hb, const int* __restrict__ idxmap,
    __hip_bfloat16* __restrict__ out,                 // padded (10,130,130,32)
    const __hip_bfloat16* __restrict__ wf, const float* __restrict__ bns,
    const float* __restrict__ occ) {
    int wave = (blockIdx.x * 256 + threadIdx.x) >> 6;  // 8192 waves
    int lane = threadIdx.x & 63;
    int tw = wave & 7; int r = wave >> 3;
    int h = r & 127;   int d = r >> 7;
    int w0 = tw * 16;
    int q = lane >> 4, n = lane & 15;

    f32x4 acc0 = {0.f, 0.f, 0.f, 0.f}, acc1 = {0.f, 0.f, 0.f, 0.f};
    const float* op = occ + ((size_t)(d * 128 + h)) * 128 + w0;
    float ocn = op[n];
    if (__ballot(ocn != 0.f)) {
#pragma unroll
        for (int kd = 0; kd < 3; ++kd) {
            int id = d * 2 + kd - 1;
            if (id < 0) continue;
#pragma unroll
            for (int kh = 0; kh < 3; ++kh) {
                int ih = h * 2 + kh - 1;
                if (ih < 0) continue;
                const int* ip = idxmap + ((size_t)id * 256 + ih) * 256;
#pragma unroll
                for (int kw = 0; kw < 3; ++kw) {
                    int tap = (kd * 3 + kh) * 3 + kw;
                    int iw = (w0 + n) * 2 + kw - 1;
                    int v = (iw >= 0) ? ip[iw] : -1;
                    int vv = (v >= 0) ? v : 40000;              // row 40000 = zeros
                    bf16x8 A = ldfrag(hb + (size_t)vv * 32 + q * 8);
                    acc0 = __builtin_amdgcn_mfma_f32_16x16x32_bf16(
                        A, ldfrag(wf + ((tap * 2 + 0) << 9) + lane * 8), acc0, 0, 0, 0);
                    acc1 = __builtin_amdgcn_mfma_f32_16x16x32_bf16(
                        A, ldfrag(wf + ((tap * 2 + 1) << 9) + lane * 8), acc1, 0, 0, 0);
                }
            }
        }
    }
#pragma unroll
    for (int half = 0; half < 2; ++half) {
        int co = half * 16 + n;
        float s = bns[co], b = bns[32 + co];
        f32x4 a = half ? acc1 : acc0;
#pragma unroll
        for (int r2 = 0; r2 < 4; ++r2) {
            int mm = q * 4 + r2;
            float oc = op[mm];
            float vv = fmaxf(a[r2] * s + b, 0.f) * oc;
            out[((size_t)((d + 1) * 130 + (h + 1)) * 130 + (w0 + mm + 1)) * 32 + co] =
                __float2bfloat16(vv);
        }
    }
}

// ---------------- dense implicit-GEMM MFMA conv (padded NDHWC bf16 in/out) ----------------
template <int CIN, int COUT, int STRIDE>
__global__ __launch_bounds__(256) void conv_mfma(
    const __hip_bfloat16* __restrict__ in, __hip_bfloat16* __restrict__ out,
    const __hip_bfloat16* __restrict__ wf, const float* __restrict__ bns,
    const float* __restrict__ occ,
    int Hp, int Wp, int Do, int Ho, int Wo, int OHp, int OWp) {
    constexpr int KB = CIN / 32, NH = COUT / 16;
    int wave = (blockIdx.x * 256 + threadIdx.x) >> 6;
    int lane = threadIdx.x & 63;
    int tiles_w = Wo >> 4;
    int tw = wave % tiles_w; int r = wave / tiles_w;
    int h = r % Ho; int d = r / Ho;
    int w0 = tw * 16;
    int q = lane >> 4, n = lane & 15;

    f32x4 acc[NH];
#pragma unroll
    for (int i = 0; i < NH; ++i) acc[i] = (f32x4){0.f, 0.f, 0.f, 0.f};

    const float* op = occ + ((size_t)(d * Ho + h)) * Wo + w0;
    float ocn = op[n];
    if (__ballot(ocn != 0.f)) {
#pragma unroll
        for (int kd = 0; kd < 3; ++kd) {
#pragma unroll
            for (int kh = 0; kh < 3; ++kh) {
#pragma unroll
                for (int kw = 0; kw < 3; ++kw) {
                    int tap = (kd * 3 + kh) * 3 + kw;
                    const __hip_bfloat16* ip = in +
                        ((size_t)((d * STRIDE + kd) * Hp + (h * STRIDE + kh)) * Wp +
                         (w0 * STRIDE + kw)) * CIN;
#pragma unroll
                    for (int kb = 0; kb < KB; ++kb) {
                        bf16x8 A = ldfrag(ip + (n * STRIDE) * CIN + kb * 32 + q * 8);
#pragma unroll
                        for (int half = 0; half < NH; ++half)
                            acc[half] = __builtin_amdgcn_mfma_f32_16x16x32_bf16(
                                A,
                                ldfrag(wf + (((tap * KB + kb) * NH + half) << 9) + lane * 8),
                                acc[half], 0, 0, 0);
                    }
                }
            }
        }
    }
#pragma unroll
    for (int half = 0; half < NH; ++half) {
        int co = half * 16 + n;
        float s = bns[co], b = bns[COUT + co];
#pragma unroll
        for (int r2 = 0; r2 < 4; ++r2) {
            int mm = q * 4 + r2;
            float oc = op[mm];
            float vv = fmaxf(acc[half][r2] * s + b, 0.f) * oc;
            out[((size_t)((d + 1) * OHp + (h + 1)) * OWp + (w0 + mm + 1)) * COUT + co] =
                __float2bfloat16(vv);
        }
    }
}

// ---------------- final conv 64->128, NCDHW typed output ----------------
__global__ __launch_bounds__(256) void conv_out_mfma(
    const __hip_bfloat16* __restrict__ in,            // padded (4,34,34,64)
    void* __restrict__ outv,
    const __hip_bfloat16* __restrict__ wf, const float* __restrict__ bns,
    const float* __restrict__ occ, const int* __restrict__ flagp) {
    constexpr int KB = 2, NH = 8;
    int wave = (blockIdx.x * 256 + threadIdx.x) >> 6;  // 128 waves
    int lane = threadIdx.x & 63;
    int tw = wave & 1; int r = wave >> 1;
    int h = r & 31;    int d = r >> 5;
    int w0 = tw * 16;
    int q = lane >> 4, n = lane & 15;

    f32x4 acc[NH];
#pragma unroll
    for (int i = 0; i < NH; ++i) acc[i] = (f32x4){0.f, 0.f, 0.f, 0.f};

    const float* op = occ + ((size_t)(d * 32 + h)) * 32 + w0;
    float ocn = op[n];
    if (__ballot(ocn != 0.f)) {
#pragma unroll
        for (int kd = 0; kd < 3; ++kd) {
#pragma unroll
            for (int kh = 0; kh < 3; ++kh) {
#pragma unroll
                for (int kw = 0; kw < 3; ++kw) {
                    int tap = (kd * 3 + kh) * 3 + kw;
                    const __hip_bfloat16* ip = in +
                        ((size_t)((d + kd) * 34 + (h + kh)) * 34 + (w0 + kw)) * 64;
#pragma unroll
                    for (int kb = 0; kb < KB; ++kb) {
                        bf16x8 A = ldfrag(ip + n * 64 + kb * 32 + q * 8);
#pragma unroll
                        for (int half = 0; half < NH; ++half)
                            acc[half] = __builtin_amdgcn_mfma_f32_16x16x32_bf16(
                                A,
                                ldfrag(wf + (((tap * KB + kb) * NH + half) << 9) + lane * 8),
                                acc[half], 0, 0, 0);
                    }
                }
            }
        }
    }
    int bf = *flagp;
#pragma unroll
    for (int half = 0; half < NH; ++half) {
        int co = half * 16 + n;
        float s = bns[co], b = bns[128 + co];
#pragma unroll
        for (int r2 = 0; r2 < 4; ++r2) {
            int mm = q * 4 + r2;
            float oc = op[mm];
            float vv = fmaxf(acc[half][r2] * s + b, 0.f) * oc;
            size_t off = (size_t)co * 2048 + ((size_t)(d * 32 + h)) * 32 + (w0 + mm);
            if (bf) ((__hip_bfloat16*)outv)[off] = __float2bfloat16(vv);
            else    ((float*)outv)[off] = vv;
        }
    }
}

// ---------------- launch ----------------
extern "C" void kernel_launch(void* const* d_in, const int* in_sizes, int n_in,
                              void* d_out, int out_size, void* d_ws, size_t ws_size,
                              hipStream_t stream) {
    const void* points = d_in[0];
    const void* voxels = d_in[1];
    const void* w_in   = d_in[2];
    const void* s_in   = d_in[3];
    const void* t_in   = d_in[4];
    const int* coors = (const int*)d_in[35];
    const int* p2v   = (const int*)d_in[36];

    char* ws = (char*)d_ws;
    __hip_bfloat16* wf   = (__hip_bfloat16*)(ws + 0);          // 912,384 bf16
    float*          bn   = (float*)(ws + 1835008);             // 1,216 f32
    __hip_bfloat16* hbuf = (__hip_bfloat16*)(ws + 4194304);    // 40001*32 bf16
    int*   idxmap = (int*)(ws + 8388608);                      // 4 MiB
    __hip_bfloat16* xP0A = (__hip_bfloat16*)(ws + 12582912);   // 10*130*130*32
    __hip_bfloat16* xP0B = (__hip_bfloat16*)(ws + 23398912);
    __hip_bfloat16* xP1A = (__hip_bfloat16*)(ws + 34214912);   // 6*66*66*64
    __hip_bfloat16* xP1B = (__hip_bfloat16*)(ws + 37560320);
    __hip_bfloat16* xP2A = (__hip_bfloat16*)(ws + 40905728);   // 4*34*34*64
    __hip_bfloat16* xP2B = (__hip_bfloat16*)(ws + 41497600);
    float* occ1 = (float*)(ws + 42089472);
    float* occ2 = (float*)(ws + 42613760);
    float* occ3 = (float*)(ws + 42679296);
    float* occ4 = (float*)(ws + 42687488);
    int*   cnt  = (int*)(ws + 42695680);
    int*   mini = (int*)(ws + 42855680);
    int*   list = (int*)(ws + 43015680);
    int*   flag = (int*)(ws + 46215680);

    (void)hipMemsetAsync(idxmap, 0xFF, 4194304, stream);
    (void)hipMemsetAsync(cnt, 0, 160000, stream);
    (void)hipMemsetAsync(mini, 0x7f, 160000, stream);
    (void)hipMemsetAsync(hbuf, 0, 2560064, stream);
    (void)hipMemsetAsync(xP0A, 0, 29506560, stream);   // all six activation buffers

    detect_dtype<<<1, 64, 0, stream>>>(points, flag);

    static const int widx[30] = {5,6,7, 8,9,10, 11,12,13, 14,15,16, 17,18,19,
                                 20,21,22, 23,24,25, 26,27,28, 29,30,31, 32,33,34};
    static const int wnn[30]  = {27648,32,32, 27648,32,32, 27648,32,32,
                                 55296,64,64, 110592,64,64, 110592,64,64,
                                 110592,64,64, 110592,64,64, 110592,64,64,
                                 221184,128,128};
    static const int woff[30] = {0,0,32, 27648,64,96, 55296,128,160,
                                 82944,192,256, 138240,320,384, 248832,448,512,
                                 359424,576,640, 470016,704,768, 580608,832,896,
                                 691200,960,1088};
    static const int wcin[30]  = {32,0,0, 32,0,0, 32,0,0, 32,0,0, 64,0,0,
                                  64,0,0, 64,0,0, 64,0,0, 64,0,0, 64,0,0};
    static const int wcout[30] = {32,0,0, 32,0,0, 32,0,0, 64,0,0, 64,0,0,
                                  64,0,0, 64,0,0, 64,0,0, 64,0,0, 128,0,0};
    CvtArgs ca;
    for (int i = 0; i < 30; ++i)
        ca.d[i] = CvtDesc{ d_in[widx[i]], wnn[i], woff[i], wcin[i], wcout[i] };
    cvt_weights<<<dim3(864, 30), 256, 0, stream>>>(ca, wf, bn, flag);

    build_lists<<<782, 256, 0, stream>>>(p2v, cnt, mini, list, 200000);
    scatter_idx<<<157, 256, 0, stream>>>(coors, idxmap);
    vfe_kernel<<<157, 256, 0, stream>>>(points, voxels, w_in, s_in, t_in,
                                        cnt, mini, list, hbuf, flag);

    // stage 0: -> (8,128,128) x32
    pool_occ0<<<512, 256, 0, stream>>>(idxmap, occ1);
    conv0_mfma<<<2048, 256, 0, stream>>>(hbuf, idxmap, xP0A, wf + 0, bn + 0, occ1);
    conv_mfma<32, 32, 1><<<2048, 256, 0, stream>>>(
        xP0A, xP0B, wf + 27648, bn + 64, occ1, 130, 130, 8, 128, 128, 130, 130);
    conv_mfma<32, 32, 1><<<2048, 256, 0, stream>>>(
        xP0B, xP0A, wf + 55296, bn + 128, occ1, 130, 130, 8, 128, 128, 130, 130);

    // stage 1: -> (4,64,64) x64
    pool_occ<<<64, 256, 0, stream>>>(occ1, occ2, 8, 128, 128, 4, 64, 64, 2);
    conv_mfma<32, 64, 2><<<256, 256, 0, stream>>>(
        xP0A, xP1A, wf + 82944, bn + 192, occ2, 130, 130, 4, 64, 64, 66, 66);
    conv_mfma<64, 64, 1><<<256, 256, 0, stream>>>(
        xP1A, xP1B, wf + 138240, bn + 320, occ2, 66, 66, 4, 64, 64, 66, 66);
    conv_mfma<64, 64, 1><<<256, 256, 0, stream>>>(
        xP1B, xP1A, wf + 248832, bn + 448, occ2, 66, 66, 4, 64, 64, 66, 66);

    // stage 2: -> (2,32,32) x64
    pool_occ<<<8, 256, 0, stream>>>(occ2, occ3, 4, 64, 64, 2, 32, 32, 2);
    conv_mfma<64, 64, 2><<<32, 256, 0, stream>>>(
        xP1A, xP2A, wf + 359424, bn + 576, occ3, 66, 66, 2, 32, 32, 34, 34);
    conv_mfma<64, 64, 1><<<32, 256, 0, stream>>>(
        xP2A, xP2B, wf + 470016, bn + 704, occ3, 34, 34, 2, 32, 32, 34, 34);
    conv_mfma<64, 64, 1><<<32, 256, 0, stream>>>(
        xP2B, xP2A, wf + 580608, bn + 832, occ3, 34, 34, 2, 32, 32, 34, 34);

    // final: -> (128,2,32,32)
    pool_occ<<<8, 256, 0, stream>>>(occ3, occ4, 2, 32, 32, 2, 32, 32, 1);
    conv_out_mfma<<<32, 256, 0, stream>>>(xP2A, d_out, wf + 691200, bn + 960, occ4, flag);
}

// Round 6
// 437.044 us; speedup vs baseline: 5.1784x; 1.1586x over previous
//
#include <hip/hip_runtime.h>
#include <hip/hip_bf16.h>

#define DEV __device__ __forceinline__

typedef __bf16 bf16x8 __attribute__((ext_vector_type(8)));
typedef float f32x4 __attribute__((ext_vector_type(4)));

DEV float ldflex(const void* p, long i, int bf) {
    return bf ? __bfloat162float(((const __hip_bfloat16*)p)[i]) : ((const float*)p)[i];
}
DEV bf16x8 ldfrag(const __hip_bfloat16* p) { return *(const bf16x8*)(const void*)p; }

// ---------------- dtype probe ----------------
__global__ void detect_dtype(const void* probe, int* flag) {
    if (blockIdx.x == 0 && threadIdx.x == 0) {
        const unsigned short* u = (const unsigned short*)probe;
        int sane = 0;
        for (int i = 0; i < 256; ++i) {
            unsigned short v = u[i];
            int e = (v >> 7) & 0xFF;
            if (v == 0 || (e >= 107 && e <= 147)) sane++;
        }
        *flag = (sane >= 192) ? 1 : 0;   // 1 = bf16 storage
    }
}

// ---------------- weight conversion into MFMA B-fragment order ----------------
// conv weights (cin>0): wf[off + (((tap*KB+kb)*NH+half)<<9) + lane*8 + j] bf16,
//   co=half*16+n, ci=kb*32+q*8+j, lane=q*16+n.  BN (cin==0): bn[off+i] f32.
struct CvtDesc { const void* src; int n; int off; int cin; int cout; };
struct CvtArgs { CvtDesc d[30]; };

__global__ void cvt_weights(CvtArgs a, __hip_bfloat16* __restrict__ wf,
                            float* __restrict__ bn, const int* __restrict__ flagp) {
    CvtDesc de = a.d[blockIdx.y];
    int i = blockIdx.x * 256 + threadIdx.x;
    if (i >= de.n) return;
    float v = ldflex(de.src, i, *flagp);
    if (de.cin == 0) { bn[de.off + i] = v; return; }
    int cin = de.cin;
    int KB = cin >> 5, NH = de.cout >> 4;
    int co = i / (cin * 27);
    int rem = i % (cin * 27);
    int ci = rem / 27, tap = rem % 27;
    int kb = ci >> 5, q = (ci >> 3) & 3, j = ci & 7;
    int half = co >> 4, n = co & 15, lane = q * 16 + n;
    (void)KB;
    wf[de.off + ((((tap * KB + kb) * NH + half) << 9) + lane * 8 + j)] = __float2bfloat16(v);
}

// ---------------- point lists ----------------
__global__ void build_lists(const int* __restrict__ p2v, int* __restrict__ cnt,
                            int* __restrict__ mini, int* __restrict__ list, int n) {
    int i = blockIdx.x * blockDim.x + threadIdx.x;
    if (i >= n) return;
    int v = p2v[i];
    int slot = atomicAdd(&cnt[v], 1);
    if (slot < 20) list[v * 20 + slot] = i;
    atomicMin(&mini[v], i);
}

__global__ void scatter_idx(const int* __restrict__ coors, int* __restrict__ idxmap) {
    int v = blockIdx.x * blockDim.x + threadIdx.x;
    if (v >= 40000) return;
    int x = coors[v * 4 + 1], y = coors[v * 4 + 2], z = coors[v * 4 + 3];
    idxmap[((size_t)z * 256 + y) * 256 + x] = v;
}

// ---------------- VFE: one thread per voxel, bf16 voxel-major h[v][32] ----------------
__global__ __launch_bounds__(256) void vfe_kernel(
    const void* __restrict__ points, const void* __restrict__ voxels,
    const void* __restrict__ w_in, const void* __restrict__ s_in, const void* __restrict__ t_in,
    const int* __restrict__ cnt, const int* __restrict__ mini, const int* __restrict__ list,
    __hip_bfloat16* __restrict__ hbuf, const int* __restrict__ flagp) {
    const int V = 40000, S = 20, N = 200000;
    int v = blockIdx.x * blockDim.x + threadIdx.x;
    if (v >= V) return;
    int bf = *flagp;
    float vx0 = ldflex(voxels, v * 4 + 0, bf);
    float vx1 = ldflex(voxels, v * 4 + 1, bf);
    float vx2 = ldflex(voxels, v * 4 + 2, bf);
    float vx3 = ldflex(voxels, v * 4 + 3, bf);
    int c_ = min(cnt[v], S);
    int first = mini[v];
    float acc[32];
#pragma unroll
    for (int o = 0; o < 32; ++o) acc[o] = 0.f;

    for (int base = 0; base < c_; base += 5) {
        int kn = min(5, c_ - base);
        float f[5][8], mult[5];
#pragma unroll
        for (int k = 0; k < 5; ++k) {
            if (k < kn) {
                int p = list[v * S + base + k];
                float p0 = ldflex(points, p, bf);
                float p1 = ldflex(points, N + p, bf);
                float p2 = ldflex(points, 2 * N + p, bf);
                float p3 = ldflex(points, 3 * N + p, bf);
                f[k][0] = vx0 - p0; f[k][1] = vx1 - p1; f[k][2] = vx2 - p2; f[k][3] = vx3 - p3;
                f[k][4] = p0; f[k][5] = p1; f[k][6] = p2; f[k][7] = p3;
                mult[k] = (p == first) ? (float)(S - c_ + 1) : 1.f;
            } else {
#pragma unroll
                for (int c = 0; c < 8; ++c) f[k][c] = 0.f;
                mult[k] = 0.f;
            }
        }
#pragma unroll 4
        for (int o = 0; o < 32; ++o) {
            float w[8];
#pragma unroll
            for (int c = 0; c < 8; ++c) w[c] = ldflex(w_in, o * 8 + c, bf);
            float sc = ldflex(s_in, o, bf), bi = ldflex(t_in, o, bf);
#pragma unroll
            for (int k = 0; k < 5; ++k) {
                float d = f[k][0] * w[0] + f[k][1] * w[1] + f[k][2] * w[2] + f[k][3] * w[3] +
                          f[k][4] * w[4] + f[k][5] * w[5] + f[k][6] * w[6] + f[k][7] * w[7];
                acc[o] += fmaxf(d * sc + bi, 0.f) * mult[k];
            }
        }
    }
#pragma unroll
    for (int o = 0; o < 32; ++o)
        hbuf[(size_t)v * 32 + o] = __float2bfloat16(acc[o] * 0.05f);
}

// ---------------- occupancy pools ----------------
__global__ void pool_occ0(const int* __restrict__ idxmap, float* __restrict__ out) {
    int idx = blockIdx.x * blockDim.x + threadIdx.x;
    if (idx >= 8 * 128 * 128) return;
    int w = idx % 128; int r = idx / 128;
    int h = r % 128;   int d = r / 128;
    float m = 0.f;
    for (int kd = 0; kd < 3; ++kd) {
        int id = d * 2 + kd - 1;
        if (id < 0 || id >= 16) continue;
        for (int kh = 0; kh < 3; ++kh) {
            int ih = h * 2 + kh - 1;
            if (ih < 0 || ih >= 256) continue;
            for (int kw = 0; kw < 3; ++kw) {
                int iw = w * 2 + kw - 1;
                if (iw < 0 || iw >= 256) continue;
                if (idxmap[((size_t)id * 256 + ih) * 256 + iw] >= 0) m = 1.f;
            }
        }
    }
    out[idx] = m;
}

__global__ void pool_occ(const float* __restrict__ in, float* __restrict__ out,
                         int Di, int Hi, int Wi, int Do, int Ho, int Wo, int stride) {
    int idx = blockIdx.x * blockDim.x + threadIdx.x;
    int total = Do * Ho * Wo;
    if (idx >= total) return;
    int w = idx % Wo; int r = idx / Wo;
    int h = r % Ho;   int d = r / Ho;
    float m = 0.f;
    for (int kd = 0; kd < 3; ++kd) {
        int id = d * stride + kd - 1;
        if (id < 0 || id >= Di) continue;
        for (int kh = 0; kh < 3; ++kh) {
            int ih = h * stride + kh - 1;
            if (ih < 0 || ih >= Hi) continue;
            for (int kw = 0; kw < 3; ++kw) {
                int iw = w * stride + kw - 1;
                if (iw < 0 || iw >= Wi) continue;
                m = fmaxf(m, in[((size_t)id * Hi + ih) * Wi + iw]);
            }
        }
    }
    out[idx] = m;
}

// ---------------- conv0: sparse gather implicit-GEMM MFMA ----------------
__global__ __launch_bounds__(256) void conv0_mfma(
    const __hip_bfloat16* __restrict__ hb, const int* __restrict__ idxmap,
    __hip_bfloat16* __restrict__ out,                 // padded (10,130,130,32)
    const __hip_bfloat16* __restrict__ wf, const float* __restrict__ bns,
    const float* __restrict__ occ) {
    int wave = (blockIdx.x * 256 + threadIdx.x) >> 6;  // 8192 waves
    int lane = threadIdx.x & 63;
    int tw = wave & 7; int r = wave >> 3;
    int h = r & 127;   int d = r >> 7;
    int w0 = tw * 16;
    int q = lane >> 4, n = lane & 15;

    f32x4 acc0 = {0.f, 0.f, 0.f, 0.f}, acc1 = {0.f, 0.f, 0.f, 0.f};
    const float* op = occ + ((size_t)(d * 128 + h)) * 128 + w0;
    float ocn = op[n];
    if (__ballot(ocn != 0.f)) {
#pragma unroll
        for (int kd = 0; kd < 3; ++kd) {
            int id = d * 2 + kd - 1;
            if (id < 0) continue;
#pragma unroll
            for (int kh = 0; kh < 3; ++kh) {
                int ih = h * 2 + kh - 1;
                if (ih < 0) continue;
                const int* ip = idxmap + ((size_t)id * 256 + ih) * 256;
#pragma unroll
                for (int kw = 0; kw < 3; ++kw) {
                    int tap = (kd * 3 + kh) * 3 + kw;
                    int iw = (w0 + n) * 2 + kw - 1;
                    int v = (iw >= 0) ? ip[iw] : -1;
                    int vv = (v >= 0) ? v : 40000;              // row 40000 = zeros
                    bf16x8 A = ldfrag(hb + (size_t)vv * 32 + q * 8);
                    acc0 = __builtin_amdgcn_mfma_f32_16x16x32_bf16(
                        A, ldfrag(wf + ((tap * 2 + 0) << 9) + lane * 8), acc0, 0, 0, 0);
                    acc1 = __builtin_amdgcn_mfma_f32_16x16x32_bf16(
                        A, ldfrag(wf + ((tap * 2 + 1) << 9) + lane * 8), acc1, 0, 0, 0);
                }
            }
        }
    }
#pragma unroll
    for (int half = 0; half < 2; ++half) {
        int co = half * 16 + n;
        float s = bns[co], b = bns[32 + co];
        f32x4 a = half ? acc1 : acc0;
#pragma unroll
        for (int r2 = 0; r2 < 4; ++r2) {
            int mm = q * 4 + r2;
            float oc = op[mm];
            float vv = fmaxf(a[r2] * s + b, 0.f) * oc;
            out[((size_t)((d + 1) * 130 + (h + 1)) * 130 + (w0 + mm + 1)) * 32 + co] =
                __float2bfloat16(vv);
        }
    }
}

// ---------------- dense implicit-GEMM MFMA conv (padded NDHWC bf16 in/out) ----------------
// NHP = cout-halves per wave; NH/NHP half-groups are spread across waves (low bits of
// the global wave id) so small grids still fill the machine.
template <int CIN, int COUT, int STRIDE, int NHP>
__global__ __launch_bounds__(256) void conv_mfma(
    const __hip_bfloat16* __restrict__ in, __hip_bfloat16* __restrict__ out,
    const __hip_bfloat16* __restrict__ wf, const float* __restrict__ bns,
    const float* __restrict__ occ,
    int Hp, int Wp, int Do, int Ho, int Wo, int OHp, int OWp) {
    constexpr int KB = CIN / 32, NH = COUT / 16, NG = NH / NHP;
    int gw = (blockIdx.x * 256 + threadIdx.x) >> 6;
    int lane = threadIdx.x & 63;
    int hg = gw & (NG - 1);
    int wave = gw / NG;
    int tiles_w = Wo >> 4;
    int tw = wave % tiles_w; int r = wave / tiles_w;
    int h = r % Ho; int d = r / Ho;
    int w0 = tw * 16;
    int q = lane >> 4, n = lane & 15;

    f32x4 acc[NHP];
#pragma unroll
    for (int i = 0; i < NHP; ++i) acc[i] = (f32x4){0.f, 0.f, 0.f, 0.f};

    const float* op = occ + ((size_t)(d * Ho + h)) * Wo + w0;
    float ocn = op[n];
    if (__ballot(ocn != 0.f)) {
#pragma unroll
        for (int kd = 0; kd < 3; ++kd) {
#pragma unroll
            for (int kh = 0; kh < 3; ++kh) {
#pragma unroll
                for (int kw = 0; kw < 3; ++kw) {
                    int tap = (kd * 3 + kh) * 3 + kw;
                    const __hip_bfloat16* ip = in +
                        ((size_t)((d * STRIDE + kd) * Hp + (h * STRIDE + kh)) * Wp +
                         (w0 * STRIDE + kw)) * CIN;
#pragma unroll
                    for (int kb = 0; kb < KB; ++kb) {
                        bf16x8 A = ldfrag(ip + (n * STRIDE) * CIN + kb * 32 + q * 8);
#pragma unroll
                        for (int i = 0; i < NHP; ++i) {
                            int half = hg * NHP + i;
                            acc[i] = __builtin_amdgcn_mfma_f32_16x16x32_bf16(
                                A,
                                ldfrag(wf + (((tap * KB + kb) * NH + half) << 9) + lane * 8),
                                acc[i], 0, 0, 0);
                        }
                    }
                }
            }
        }
    }
#pragma unroll
    for (int i = 0; i < NHP; ++i) {
        int co = (hg * NHP + i) * 16 + n;
        float s = bns[co], b = bns[COUT + co];
#pragma unroll
        for (int r2 = 0; r2 < 4; ++r2) {
            int mm = q * 4 + r2;
            float oc = op[mm];
            float vv = fmaxf(acc[i][r2] * s + b, 0.f) * oc;
            out[((size_t)((d + 1) * OHp + (h + 1)) * OWp + (w0 + mm + 1)) * COUT + co] =
                __float2bfloat16(vv);
        }
    }
}

// ---------------- final conv 64->128, NCDHW typed output, half-split across waves ---------
__global__ __launch_bounds__(256) void conv_out_mfma(
    const __hip_bfloat16* __restrict__ in,            // padded (4,34,34,64)
    void* __restrict__ outv,
    const __hip_bfloat16* __restrict__ wf, const float* __restrict__ bns,
    const float* __restrict__ occ, const int* __restrict__ flagp) {
    constexpr int KB = 2, NH = 8;
    int gw = (blockIdx.x * 256 + threadIdx.x) >> 6;   // 1024 waves
    int lane = threadIdx.x & 63;
    int hg = gw & 7;          // cout half 0..7
    int wave = gw >> 3;       // spatial tile 0..127
    int tw = wave & 1; int r = wave >> 1;
    int h = r & 31;    int d = r >> 5;
    int w0 = tw * 16;
    int q = lane >> 4, n = lane & 15;

    f32x4 acc = {0.f, 0.f, 0.f, 0.f};
    const float* op = occ + ((size_t)(d * 32 + h)) * 32 + w0;
    float ocn = op[n];
    if (__ballot(ocn != 0.f)) {
#pragma unroll
        for (int kd = 0; kd < 3; ++kd) {
#pragma unroll
            for (int kh = 0; kh < 3; ++kh) {
#pragma unroll
                for (int kw = 0; kw < 3; ++kw) {
                    int tap = (kd * 3 + kh) * 3 + kw;
                    const __hip_bfloat16* ip = in +
                        ((size_t)((d + kd) * 34 + (h + kh)) * 34 + (w0 + kw)) * 64;
#pragma unroll
                    for (int kb = 0; kb < KB; ++kb) {
                        bf16x8 A = ldfrag(ip + n * 64 + kb * 32 + q * 8);
                        acc = __builtin_amdgcn_mfma_f32_16x16x32_bf16(
                            A, ldfrag(wf + (((tap * KB + kb) * NH + hg) << 9) + lane * 8),
                            acc, 0, 0, 0);
                    }
                }
            }
        }
    }
    int bf = *flagp;
    int co = hg * 16 + n;
    float s = bns[co], b = bns[128 + co];
#pragma unroll
    for (int r2 = 0; r2 < 4; ++r2) {
        int mm = q * 4 + r2;
        float oc = op[mm];
        float vv = fmaxf(acc[r2] * s + b, 0.f) * oc;
        size_t off = (size_t)co * 2048 + ((size_t)(d * 32 + h)) * 32 + (w0 + mm);
        if (bf) ((__hip_bfloat16*)outv)[off] = __float2bfloat16(vv);
        else    ((float*)outv)[off] = vv;
    }
}

// ---------------- launch ----------------
extern "C" void kernel_launch(void* const* d_in, const int* in_sizes, int n_in,
                              void* d_out, int out_size, void* d_ws, size_t ws_size,
                              hipStream_t stream) {
    const void* points = d_in[0];
    const void* voxels = d_in[1];
    const void* w_in   = d_in[2];
    const void* s_in   = d_in[3];
    const void* t_in   = d_in[4];
    const int* coors = (const int*)d_in[35];
    const int* p2v   = (const int*)d_in[36];

    char* ws = (char*)d_ws;
    __hip_bfloat16* wf   = (__hip_bfloat16*)(ws + 0);          // 912,384 bf16
    float*          bn   = (float*)(ws + 1835008);             // 1,216 f32
    __hip_bfloat16* hbuf = (__hip_bfloat16*)(ws + 4194304);    // 40001*32 bf16
    int*   idxmap = (int*)(ws + 8388608);                      // 4 MiB
    __hip_bfloat16* xP0A = (__hip_bfloat16*)(ws + 12582912);   // 10*130*130*32
    __hip_bfloat16* xP0B = (__hip_bfloat16*)(ws + 23398912);
    __hip_bfloat16* xP1A = (__hip_bfloat16*)(ws + 34214912);   // 6*66*66*64
    __hip_bfloat16* xP1B = (__hip_bfloat16*)(ws + 37560320);
    __hip_bfloat16* xP2A = (__hip_bfloat16*)(ws + 40905728);   // 4*34*34*64
    __hip_bfloat16* xP2B = (__hip_bfloat16*)(ws + 41497600);
    float* occ1 = (float*)(ws + 42089472);
    float* occ2 = (float*)(ws + 42613760);
    float* occ3 = (float*)(ws + 42679296);
    float* occ4 = (float*)(ws + 42687488);
    int*   cnt  = (int*)(ws + 42695680);
    int*   mini = (int*)(ws + 42855680);
    int*   list = (int*)(ws + 43015680);
    int*   flag = (int*)(ws + 46215680);

    (void)hipMemsetAsync(idxmap, 0xFF, 4194304, stream);
    (void)hipMemsetAsync(cnt, 0, 160000, stream);
    (void)hipMemsetAsync(mini, 0x7f, 160000, stream);
    (void)hipMemsetAsync(hbuf, 0, 2560064, stream);
    (void)hipMemsetAsync(xP0A, 0, 29506560, stream);   // all six activation buffers

    detect_dtype<<<1, 64, 0, stream>>>(points, flag);

    static const int widx[30] = {5,6,7, 8,9,10, 11,12,13, 14,15,16, 17,18,19,
                                 20,21,22, 23,24,25, 26,27,28, 29,30,31, 32,33,34};
    static const int wnn[30]  = {27648,32,32, 27648,32,32, 27648,32,32,
                                 55296,64,64, 110592,64,64, 110592,64,64,
                                 110592,64,64, 110592,64,64, 110592,64,64,
                                 221184,128,128};
    static const int woff[30] = {0,0,32, 27648,64,96, 55296,128,160,
                                 82944,192,256, 138240,320,384, 248832,448,512,
                                 359424,576,640, 470016,704,768, 580608,832,896,
                                 691200,960,1088};
    static const int wcin[30]  = {32,0,0, 32,0,0, 32,0,0, 32,0,0, 64,0,0,
                                  64,0,0, 64,0,0, 64,0,0, 64,0,0, 64,0,0};
    static const int wcout[30] = {32,0,0, 32,0,0, 32,0,0, 64,0,0, 64,0,0,
                                  64,0,0, 64,0,0, 64,0,0, 64,0,0, 128,0,0};
    CvtArgs ca;
    for (int i = 0; i < 30; ++i)
        ca.d[i] = CvtDesc{ d_in[widx[i]], wnn[i], woff[i], wcin[i], wcout[i] };
    cvt_weights<<<dim3(864, 30), 256, 0, stream>>>(ca, wf, bn, flag);

    build_lists<<<782, 256, 0, stream>>>(p2v, cnt, mini, list, 200000);
    scatter_idx<<<157, 256, 0, stream>>>(coors, idxmap);
    vfe_kernel<<<157, 256, 0, stream>>>(points, voxels, w_in, s_in, t_in,
                                        cnt, mini, list, hbuf, flag);

    // stage 0: -> (8,128,128) x32   (8192 waves, NHP=2 — already at occupancy cap)
    pool_occ0<<<512, 256, 0, stream>>>(idxmap, occ1);
    conv0_mfma<<<2048, 256, 0, stream>>>(hbuf, idxmap, xP0A, wf + 0, bn + 0, occ1);
    conv_mfma<32, 32, 1, 2><<<2048, 256, 0, stream>>>(
        xP0A, xP0B, wf + 27648, bn + 64, occ1, 130, 130, 8, 128, 128, 130, 130);
    conv_mfma<32, 32, 1, 2><<<2048, 256, 0, stream>>>(
        xP0B, xP0A, wf + 55296, bn + 128, occ1, 130, 130, 8, 128, 128, 130, 130);

    // stage 1: -> (4,64,64) x64   (1024 tiles × 4 half-groups = 4096 waves)
    pool_occ<<<64, 256, 0, stream>>>(occ1, occ2, 8, 128, 128, 4, 64, 64, 2);
    conv_mfma<32, 64, 2, 1><<<1024, 256, 0, stream>>>(
        xP0A, xP1A, wf + 82944, bn + 192, occ2, 130, 130, 4, 64, 64, 66, 66);
    conv_mfma<64, 64, 1, 1><<<1024, 256, 0, stream>>>(
        xP1A, xP1B, wf + 138240, bn + 320, occ2, 66, 66, 4, 64, 64, 66, 66);
    conv_mfma<64, 64, 1, 1><<<1024, 256, 0, stream>>>(
        xP1B, xP1A, wf + 248832, bn + 448, occ2, 66, 66, 4, 64, 64, 66, 66);

    // stage 2: -> (2,32,32) x64   (128 tiles × 4 half-groups = 512 waves)
    pool_occ<<<8, 256, 0, stream>>>(occ2, occ3, 4, 64, 64, 2, 32, 32, 2);
    conv_mfma<64, 64, 2, 1><<<128, 256, 0, stream>>>(
        xP1A, xP2A, wf + 359424, bn + 576, occ3, 66, 66, 2, 32, 32, 34, 34);
    conv_mfma<64, 64, 1, 1><<<128, 256, 0, stream>>>(
        xP2A, xP2B, wf + 470016, bn + 704, occ3, 34, 34, 2, 32, 32, 34, 34);
    conv_mfma<64, 64, 1, 1><<<128, 256, 0, stream>>>(
        xP2B, xP2A, wf + 580608, bn + 832, occ3, 34, 34, 2, 32, 32, 34, 34);

    // final: -> (128,2,32,32)   (128 tiles × 8 halves = 1024 waves)
    pool_occ<<<8, 256, 0, stream>>>(occ3, occ4, 2, 32, 32, 2, 32, 32, 1);
    conv_out_mfma<<<256, 256, 0, stream>>>(xP2A, d_out, wf + 691200, bn + 960, occ4, flag);
}